// Round 1
// baseline (1431.570 us; speedup 1.0000x reference)
//
#include <hip/hip_runtime.h>
#include <math.h>

#define NEG_SLOPE 0.2f

// atomic float max via int/uint trick (works for mixed signs, init -inf)
__device__ __forceinline__ void atomicMaxF32(float* addr, float val) {
  if (val >= 0.f) {
    atomicMax((int*)addr, __float_as_int(val));
  } else {
    atomicMin((unsigned int*)addr, __float_as_uint(val));
  }
}

// ---------------- K0: init emax=-inf, asum=0, agg=0 ----------------
__global__ void k_init(float* __restrict__ emax, float* __restrict__ asum,
                       float* __restrict__ agg, int n) {
  int i = blockIdx.x * 256 + threadIdx.x;
  if (i < n * 4) { emax[i] = -INFINITY; asum[i] = 0.f; }
  if (i < n * 64) agg[i] = 0.f;
}

// ---------------- K1: node transforms: ni, nj, hq ----------------
// ni = hE@Wni, nj = hE@Wnj, hp = hE@Wnode + bnode,
// hq[n,h,:] = hp[n,h,:] @ Wpn[h*64:(h+1)*64, :]
// Tile: 32 nodes x 256 cols, 256 threads, thread = 4 nodes x 8 cols.
__global__ __launch_bounds__(256) void k_node(
    const float* __restrict__ hE,
    const float* __restrict__ Wni, const float* __restrict__ Wnj,
    const float* __restrict__ Wnode, const float* __restrict__ bnode,
    const float* __restrict__ Wpn,
    float* __restrict__ ni, float* __restrict__ nj, float* __restrict__ hq,
    int n) {
  __shared__ float hEt[64 * 36];    // transposed [k][m], stride 36 (pad)
  __shared__ float hpl[32 * 260];   // hp tile [m][c], stride 260 (pad)
  const int tid = threadIdx.x;
  const int n0 = blockIdx.x * 32;

#pragma unroll
  for (int i = 0; i < 8; ++i) {
    int flat = tid + i * 256;
    int m = flat >> 6, k = flat & 63;
    hEt[k * 36 + m] = (n0 + m < n) ? hE[(size_t)(n0 + m) * 64 + k] : 0.f;
  }
  __syncthreads();

  const int tm = tid >> 5, tc = tid & 31, c0 = tc * 8;

  for (int pass = 0; pass < 3; ++pass) {
    const float* W = (pass == 0) ? Wni : (pass == 1) ? Wnj : Wnode;
    float acc[4][8];
#pragma unroll
    for (int mm = 0; mm < 4; ++mm)
#pragma unroll
      for (int j = 0; j < 8; ++j) acc[mm][j] = 0.f;

    for (int k = 0; k < 64; ++k) {
      float4 h4 = *(const float4*)&hEt[k * 36 + tm * 4];
      float4 w0 = *(const float4*)&W[k * 256 + c0];
      float4 w1 = *(const float4*)&W[k * 256 + c0 + 4];
      float hv[4] = {h4.x, h4.y, h4.z, h4.w};
      float wv[8] = {w0.x, w0.y, w0.z, w0.w, w1.x, w1.y, w1.z, w1.w};
#pragma unroll
      for (int mm = 0; mm < 4; ++mm)
#pragma unroll
        for (int j = 0; j < 8; ++j) acc[mm][j] += hv[mm] * wv[j];
    }

    if (pass < 2) {
      float* out = (pass == 0) ? ni : nj;
#pragma unroll
      for (int mm = 0; mm < 4; ++mm) {
        int m = tm * 4 + mm;
        if (n0 + m < n) {
          *(float4*)&out[(size_t)(n0 + m) * 256 + c0] =
              make_float4(acc[mm][0], acc[mm][1], acc[mm][2], acc[mm][3]);
          *(float4*)&out[(size_t)(n0 + m) * 256 + c0 + 4] =
              make_float4(acc[mm][4], acc[mm][5], acc[mm][6], acc[mm][7]);
        }
      }
    } else {
#pragma unroll
      for (int mm = 0; mm < 4; ++mm) {
        int m = tm * 4 + mm;
#pragma unroll
        for (int j = 0; j < 8; ++j)
          hpl[m * 260 + c0 + j] = acc[mm][j] + bnode[c0 + j];
      }
    }
  }
  __syncthreads();

  // hq pass: per-head 64x64 projection. col c0+j lives in head hh.
  const int hh = tc >> 3, dc0 = (tc & 7) * 8;
  float acc[4][8];
#pragma unroll
  for (int mm = 0; mm < 4; ++mm)
#pragma unroll
    for (int j = 0; j < 8; ++j) acc[mm][j] = 0.f;

  for (int k = 0; k < 64; ++k) {
    float4 w0 = *(const float4*)&Wpn[(size_t)(hh * 64 + k) * 64 + dc0];
    float4 w1 = *(const float4*)&Wpn[(size_t)(hh * 64 + k) * 64 + dc0 + 4];
    float wv[8] = {w0.x, w0.y, w0.z, w0.w, w1.x, w1.y, w1.z, w1.w};
#pragma unroll
    for (int mm = 0; mm < 4; ++mm) {
      float hv = hpl[(tm * 4 + mm) * 260 + hh * 64 + k];
#pragma unroll
      for (int j = 0; j < 8; ++j) acc[mm][j] += hv * wv[j];
    }
  }
#pragma unroll
  for (int mm = 0; mm < 4; ++mm) {
    int m = tm * 4 + mm;
    if (n0 + m < n) {
      *(float4*)&hq[(size_t)(n0 + m) * 256 + c0] =
          make_float4(acc[mm][0], acc[mm][1], acc[mm][2], acc[mm][3]);
      *(float4*)&hq[(size_t)(n0 + m) * 256 + c0 + 4] =
          make_float4(acc[mm][4], acc[mm][5], acc[mm][6], acc[mm][7]);
    }
  }
}

// ---------------- K2: edge kernel ----------------
// f = leaky(ni[src] + nj[dst] + hH@Wfij); e = head-dots(f, attn);
// atomicMax emax; out1 = hH + f@Wpe + bpe. f stays in LDS (never to HBM).
// Tile: 32 edges. Assumes E % 32 == 0.
__global__ __launch_bounds__(256) void k_edge(
    const float* __restrict__ hH,
    const int* __restrict__ src, const int* __restrict__ dst,
    const float* __restrict__ Wfij, const float* __restrict__ attn,
    const float* __restrict__ Wpe, const float* __restrict__ bpe,
    const float* __restrict__ ni, const float* __restrict__ nj,
    float* __restrict__ e_ws, float* __restrict__ emax,
    float* __restrict__ out1) {
  __shared__ float hht[64 * 36];    // transposed hH tile [k][m], stride 36
  __shared__ float flds[32 * 256];  // f tile [m][c]
  __shared__ int s_src[32], s_dst[32];
  const int tid = threadIdx.x;
  const int e0 = blockIdx.x * 32;

  if (tid < 32) { s_src[tid] = src[e0 + tid]; s_dst[tid] = dst[e0 + tid]; }
#pragma unroll
  for (int i = 0; i < 8; ++i) {
    int flat = tid + i * 256;
    int m = flat >> 6, k = flat & 63;
    hht[k * 36 + m] = hH[(size_t)(e0 + m) * 64 + k];
  }
  __syncthreads();

  const int tm = tid >> 5, tc = tid & 31, c0 = tc * 8;
  const int hh = tc >> 3;

  float acc[4][8];
  // init with ni[src] + nj[dst] gathers
#pragma unroll
  for (int mm = 0; mm < 4; ++mm) {
    int m = tm * 4 + mm;
    const float* pni = &ni[(size_t)s_src[m] * 256 + c0];
    const float* pnj = &nj[(size_t)s_dst[m] * 256 + c0];
    float4 a0 = *(const float4*)&pni[0];
    float4 a1 = *(const float4*)&pni[4];
    float4 b0 = *(const float4*)&pnj[0];
    float4 b1 = *(const float4*)&pnj[4];
    acc[mm][0] = a0.x + b0.x; acc[mm][1] = a0.y + b0.y;
    acc[mm][2] = a0.z + b0.z; acc[mm][3] = a0.w + b0.w;
    acc[mm][4] = a1.x + b1.x; acc[mm][5] = a1.y + b1.y;
    acc[mm][6] = a1.z + b1.z; acc[mm][7] = a1.w + b1.w;
  }
  // GEMM1: += hH @ Wfij
  for (int k = 0; k < 64; ++k) {
    float4 h4 = *(const float4*)&hht[k * 36 + tm * 4];
    float4 w0 = *(const float4*)&Wfij[k * 256 + c0];
    float4 w1 = *(const float4*)&Wfij[k * 256 + c0 + 4];
    float hv[4] = {h4.x, h4.y, h4.z, h4.w};
    float wv[8] = {w0.x, w0.y, w0.z, w0.w, w1.x, w1.y, w1.z, w1.w};
#pragma unroll
    for (int mm = 0; mm < 4; ++mm)
#pragma unroll
      for (int j = 0; j < 8; ++j) acc[mm][j] += hv[mm] * wv[j];
  }
  // leaky relu
#pragma unroll
  for (int mm = 0; mm < 4; ++mm)
#pragma unroll
    for (int j = 0; j < 8; ++j)
      acc[mm][j] = (acc[mm][j] >= 0.f) ? acc[mm][j] : NEG_SLOPE * acc[mm][j];

  // attention logits: e[m][hh] = sum over head cols of f*attn
  float av[8];
  {
    float4 a0 = *(const float4*)&attn[hh * 64 + (tc & 7) * 8];
    float4 a1 = *(const float4*)&attn[hh * 64 + (tc & 7) * 8 + 4];
    av[0] = a0.x; av[1] = a0.y; av[2] = a0.z; av[3] = a0.w;
    av[4] = a1.x; av[5] = a1.y; av[6] = a1.z; av[7] = a1.w;
  }
#pragma unroll
  for (int mm = 0; mm < 4; ++mm) {
    float p = 0.f;
#pragma unroll
    for (int j = 0; j < 8; ++j) p += acc[mm][j] * av[j];
    p += __shfl_xor(p, 1);
    p += __shfl_xor(p, 2);
    p += __shfl_xor(p, 4);
    if ((tc & 7) == 0) {
      int eidx = e0 + tm * 4 + mm;
      e_ws[eidx * 4 + hh] = p;
      atomicMaxF32(&emax[s_dst[tm * 4 + mm] * 4 + hh], p);
    }
  }
  // stage f to LDS for GEMM2
#pragma unroll
  for (int mm = 0; mm < 4; ++mm) {
    int m = tm * 4 + mm;
    *(float4*)&flds[m * 256 + c0] =
        make_float4(acc[mm][0], acc[mm][1], acc[mm][2], acc[mm][3]);
    *(float4*)&flds[m * 256 + c0 + 4] =
        make_float4(acc[mm][4], acc[mm][5], acc[mm][6], acc[mm][7]);
  }
  __syncthreads();

  // GEMM2: out1[m][d] = hH[m][d] + sum_c f[m][c]*Wpe[c][d] + bpe[d]
  const int d = tid & 63, g = tid >> 6;
  float o[8];
  float bpv = bpe[d];
#pragma unroll
  for (int i = 0; i < 8; ++i) o[i] = bpv;
  for (int cc = 0; cc < 256; cc += 4) {
    float w0 = Wpe[(cc + 0) * 64 + d];
    float w1 = Wpe[(cc + 1) * 64 + d];
    float w2 = Wpe[(cc + 2) * 64 + d];
    float w3 = Wpe[(cc + 3) * 64 + d];
#pragma unroll
    for (int i = 0; i < 8; ++i) {
      float4 f4 = *(const float4*)&flds[(g * 8 + i) * 256 + cc];
      o[i] += f4.x * w0 + f4.y * w1 + f4.z * w2 + f4.w * w3;
    }
  }
#pragma unroll
  for (int i = 0; i < 8; ++i) {
    int m = g * 8 + i;
    size_t idx = (size_t)(e0 + m) * 64 + d;
    out1[idx] = o[i] + hH[idx];
  }
}

// ---------------- K3a: a = exp(e - emax[dst]); asum += a ----------------
__global__ void k3a(const float* __restrict__ e_ws, const int* __restrict__ dst,
                    const float* __restrict__ emax, float* __restrict__ a_ws,
                    float* __restrict__ asum, int E4) {
  int gid = blockIdx.x * 256 + threadIdx.x;
  if (gid >= E4) return;
  int e = gid >> 2, h = gid & 3;
  int dn = dst[e];
  float av = expf(e_ws[gid] - emax[dn * 4 + h]);
  a_ws[gid] = av;
  atomicAdd(&asum[dn * 4 + h], av);
}

// ---------------- K3b: agg[dst] += sum_h (a/asum) * hq[src,h,:] ----------------
__global__ __launch_bounds__(256) void k3b(
    const float* __restrict__ a_ws, const float* __restrict__ asum,
    const int* __restrict__ src, const int* __restrict__ dst,
    const float* __restrict__ hq, float* __restrict__ agg, int E) {
  int e = blockIdx.x * 4 + (threadIdx.x >> 6);
  if (e >= E) return;
  int d = threadIdx.x & 63;
  int sn = src[e], dn = dst[e];
  float w0 = a_ws[e * 4 + 0] / asum[dn * 4 + 0];
  float w1 = a_ws[e * 4 + 1] / asum[dn * 4 + 1];
  float w2 = a_ws[e * 4 + 2] / asum[dn * 4 + 2];
  float w3 = a_ws[e * 4 + 3] / asum[dn * 4 + 3];
  const float* hqp = &hq[(size_t)sn * 256];
  float y = w0 * hqp[d] + w1 * hqp[64 + d] + w2 * hqp[128 + d] + w3 * hqp[192 + d];
  atomicAdd(&agg[(size_t)dn * 64 + d], y);
}

// ---------------- K4: out0 = hE + agg + bp_node ----------------
__global__ void k4(const float* __restrict__ hE, const float* __restrict__ agg,
                   const float* __restrict__ bpn, float* __restrict__ out0,
                   int ND) {
  int i = blockIdx.x * 256 + threadIdx.x;
  if (i < ND) out0[i] = hE[i] + agg[i] + bpn[i & 63];
}

extern "C" void kernel_launch(void* const* d_in, const int* in_sizes, int n_in,
                              void* d_out, int out_size, void* d_ws, size_t ws_size,
                              hipStream_t stream) {
  const float* h_E    = (const float*)d_in[0];
  const float* h_H    = (const float*)d_in[1];
  const int*   src    = (const int*)d_in[2];
  const int*   dst    = (const int*)d_in[3];
  // const float* W_node = d_in[4];  // used below
  const float* W_node = (const float*)d_in[4];
  const float* b_node = (const float*)d_in[5];
  const float* W_ni   = (const float*)d_in[6];
  const float* W_nj   = (const float*)d_in[7];
  const float* W_fij  = (const float*)d_in[8];
  const float* attn   = (const float*)d_in[9];
  const float* Wp_node= (const float*)d_in[10];
  const float* bp_node= (const float*)d_in[11];
  const float* Wp_edge= (const float*)d_in[12];
  const float* bp_edge= (const float*)d_in[13];

  const int n = in_sizes[0] / 64;   // 50000 nodes
  const int e = in_sizes[1] / 64;   // 800000 edges

  // workspace layout (floats)
  size_t nHD = (size_t)n * 256;
  float* ws_ni   = (float*)d_ws;
  float* ws_nj   = ws_ni + nHD;
  float* ws_hq   = ws_nj + nHD;
  float* ws_e    = ws_hq + nHD;              // e*4
  float* ws_a    = ws_e + (size_t)e * 4;     // e*4
  float* ws_emax = ws_a + (size_t)e * 4;     // n*4
  float* ws_asum = ws_emax + (size_t)n * 4;  // n*4
  float* ws_agg  = ws_asum + (size_t)n * 4;  // n*64

  float* out0 = (float*)d_out;               // (n,64)
  float* out1 = out0 + (size_t)n * 64;       // (e,64)

  // K0: init
  {
    int total = n * 64;
    k_init<<<(total + 255) / 256, 256, 0, stream>>>(ws_emax, ws_asum, ws_agg, n);
  }
  // K1: node transforms
  {
    int blocks = (n + 31) / 32;
    k_node<<<blocks, 256, 0, stream>>>(h_E, W_ni, W_nj, W_node, b_node, Wp_node,
                                       ws_ni, ws_nj, ws_hq, n);
  }
  // K2: edge kernel (E assumed % 32 == 0; E=800000)
  {
    int blocks = e / 32;
    k_edge<<<blocks, 256, 0, stream>>>(h_H, src, dst, W_fij, attn, Wp_edge,
                                       bp_edge, ws_ni, ws_nj, ws_e, ws_emax,
                                       out1);
  }
  // K3a: softmax numerators + denominators
  {
    int total = e * 4;
    k3a<<<(total + 255) / 256, 256, 0, stream>>>(ws_e, dst, ws_emax, ws_a,
                                                 ws_asum, total);
  }
  // K3b: weighted aggregation of hq
  {
    int blocks = (e + 3) / 4;
    k3b<<<blocks, 256, 0, stream>>>(ws_a, ws_asum, src, dst, ws_hq, ws_agg, e);
  }
  // K4: node residual output
  {
    int total = n * 64;
    k4<<<(total + 255) / 256, 256, 0, stream>>>(h_E, ws_agg, bp_node, out0,
                                                total);
  }
}

// Round 2
// 807.868 us; speedup vs baseline: 1.7720x; 1.7720x over previous
//
#include <hip/hip_runtime.h>
#include <math.h>

#define NEG_SLOPE 0.2f

typedef __bf16 bf16x8 __attribute__((ext_vector_type(8)));
typedef float f32x4 __attribute__((ext_vector_type(4)));

// f32 -> bf16 bits, round-to-nearest-even
__device__ __forceinline__ ushort f2bf(float x) {
  union { float f; unsigned u; } v; v.f = x;
  unsigned r = v.u + 0x7fffu + ((v.u >> 16) & 1u);
  return (ushort)(r >> 16);
}
__device__ __forceinline__ float bf2f(ushort b) {
  union { unsigned u; float f; } v; v.u = (unsigned)b << 16;
  return v.f;
}

// atomic float max via int/uint trick (works for mixed signs, init -inf)
__device__ __forceinline__ void atomicMaxF32(float* addr, float val) {
  if (val >= 0.f) {
    atomicMax((int*)addr, __float_as_int(val));
  } else {
    atomicMin((unsigned int*)addr, __float_as_uint(val));
  }
}

// ---------------- K0: init emax=-inf, asum=0, agg=0 ----------------
__global__ void k_init(float* __restrict__ emax, float* __restrict__ asum,
                       float* __restrict__ agg, int n) {
  int i = blockIdx.x * 256 + threadIdx.x;
  if (i < n * 4) { emax[i] = -INFINITY; asum[i] = 0.f; }
  if (i < n * 64) agg[i] = 0.f;
}

// ---------------- K prep: transpose weights to bf16 ----------------
// WfT[c][k] = Wfij[k][c]  (c<256, k<64)   -> [256][64] bf16
// WpeT[n][k] = Wpe[k][n]  (k<256, n<64)   -> [64][256] bf16
__global__ void k_prep(const float* __restrict__ Wfij,
                       const float* __restrict__ Wpe,
                       ushort* __restrict__ WfT, ushort* __restrict__ WpeT) {
  int i = blockIdx.x * 256 + threadIdx.x;
  if (i < 16384) {
    int k = i >> 8, c = i & 255;   // Wfij[k][c]
    WfT[c * 64 + k] = f2bf(Wfij[i]);
    int k2 = i >> 6, n2 = i & 63;  // Wpe[k2][n2]
    WpeT[n2 * 256 + k2] = f2bf(Wpe[i]);
  }
}

// ---------------- K1: node transforms: ni(bf16), nj(bf16), hq(f32) ----------------
__global__ __launch_bounds__(256) void k_node(
    const float* __restrict__ hE,
    const float* __restrict__ Wni, const float* __restrict__ Wnj,
    const float* __restrict__ Wnode, const float* __restrict__ bnode,
    const float* __restrict__ Wpn,
    ushort* __restrict__ ni_bf, ushort* __restrict__ nj_bf,
    float* __restrict__ hq, int n) {
  __shared__ float hEt[64 * 36];    // transposed [k][m], stride 36 (pad)
  __shared__ float hpl[32 * 260];   // hp tile [m][c], stride 260 (pad)
  const int tid = threadIdx.x;
  const int n0 = blockIdx.x * 32;

#pragma unroll
  for (int i = 0; i < 8; ++i) {
    int flat = tid + i * 256;
    int m = flat >> 6, k = flat & 63;
    hEt[k * 36 + m] = (n0 + m < n) ? hE[(size_t)(n0 + m) * 64 + k] : 0.f;
  }
  __syncthreads();

  const int tm = tid >> 5, tc = tid & 31, c0 = tc * 8;

  for (int pass = 0; pass < 3; ++pass) {
    const float* W = (pass == 0) ? Wni : (pass == 1) ? Wnj : Wnode;
    float acc[4][8];
#pragma unroll
    for (int mm = 0; mm < 4; ++mm)
#pragma unroll
      for (int j = 0; j < 8; ++j) acc[mm][j] = 0.f;

    for (int k = 0; k < 64; ++k) {
      float4 h4 = *(const float4*)&hEt[k * 36 + tm * 4];
      float4 w0 = *(const float4*)&W[k * 256 + c0];
      float4 w1 = *(const float4*)&W[k * 256 + c0 + 4];
      float hv[4] = {h4.x, h4.y, h4.z, h4.w};
      float wv[8] = {w0.x, w0.y, w0.z, w0.w, w1.x, w1.y, w1.z, w1.w};
#pragma unroll
      for (int mm = 0; mm < 4; ++mm)
#pragma unroll
        for (int j = 0; j < 8; ++j) acc[mm][j] += hv[mm] * wv[j];
    }

    if (pass < 2) {
      ushort* out = (pass == 0) ? ni_bf : nj_bf;
#pragma unroll
      for (int mm = 0; mm < 4; ++mm) {
        int m = tm * 4 + mm;
        if (n0 + m < n) {
          ushort u[8];
#pragma unroll
          for (int j = 0; j < 8; ++j) u[j] = f2bf(acc[mm][j]);
          *(uint4*)&out[(size_t)(n0 + m) * 256 + c0] = *(const uint4*)u;
        }
      }
    } else {
#pragma unroll
      for (int mm = 0; mm < 4; ++mm) {
        int m = tm * 4 + mm;
#pragma unroll
        for (int j = 0; j < 8; ++j)
          hpl[m * 260 + c0 + j] = acc[mm][j] + bnode[c0 + j];
      }
    }
  }
  __syncthreads();

  // hq pass: per-head 64x64 projection. col c0+j lives in head hh.
  const int hh = tc >> 3, dc0 = (tc & 7) * 8;
  float acc[4][8];
#pragma unroll
  for (int mm = 0; mm < 4; ++mm)
#pragma unroll
    for (int j = 0; j < 8; ++j) acc[mm][j] = 0.f;

  for (int k = 0; k < 64; ++k) {
    float4 w0 = *(const float4*)&Wpn[(size_t)(hh * 64 + k) * 64 + dc0];
    float4 w1 = *(const float4*)&Wpn[(size_t)(hh * 64 + k) * 64 + dc0 + 4];
    float wv[8] = {w0.x, w0.y, w0.z, w0.w, w1.x, w1.y, w1.z, w1.w};
#pragma unroll
    for (int mm = 0; mm < 4; ++mm) {
      float hv = hpl[(tm * 4 + mm) * 260 + hh * 64 + k];
#pragma unroll
      for (int j = 0; j < 8; ++j) acc[mm][j] += hv * wv[j];
    }
  }
#pragma unroll
  for (int mm = 0; mm < 4; ++mm) {
    int m = tm * 4 + mm;
    if (n0 + m < n) {
      *(float4*)&hq[(size_t)(n0 + m) * 256 + c0] =
          make_float4(acc[mm][0], acc[mm][1], acc[mm][2], acc[mm][3]);
      *(float4*)&hq[(size_t)(n0 + m) * 256 + c0 + 4] =
          make_float4(acc[mm][4], acc[mm][5], acc[mm][6], acc[mm][7]);
    }
  }
}

// ---------------- K2: edge kernel (MFMA) ----------------
// f = leaky(ni[src] + nj[dst] + hH@Wfij); e = head-dots(f, attn);
// atomicMax emax; out1 = hH + f@Wpe + bpe. f stays in LDS.
// Tile: 32 edges, 256 threads = 4 waves. Wave w owns GEMM1 col-slab
// [w*64, w*64+64) (== head w) and GEMM2 col-tile [w*16, w*16+16).
// LDS byte layout:
//   hHb @0     : [32][64] bf16, swizzled  byte = row*128 + ((k*2)^((row&7)<<4))
//   g   @4096  : [32][256] f32, swizzled  byte = m*1024 + ((c*4)^((m&7)<<4))
//   f_bf@4096  : [32][256] bf16 (aliases g after barrier)
//                                         byte = m*512  + ((c*2)^((m&7)<<4))
//   s_src @36864, s_dst @36992
__global__ __launch_bounds__(256) void k_edge(
    const float* __restrict__ hH,
    const int* __restrict__ src, const int* __restrict__ dst,
    const ushort* __restrict__ WfT,   // [256][64] bf16
    const float* __restrict__ attn,
    const ushort* __restrict__ WpeT,  // [64][256] bf16
    const float* __restrict__ bpe,
    const ushort* __restrict__ ni_bf, const ushort* __restrict__ nj_bf,
    float* __restrict__ e_ws, float* __restrict__ emax,
    float* __restrict__ out1) {
  __shared__ __align__(16) char smem[37120];
  char* hHb = smem;
  char* gls = smem + 4096;
  int* s_src = (int*)(smem + 36864);
  int* s_dst = (int*)(smem + 36992);

  const int tid = threadIdx.x;
  const int e0 = blockIdx.x * 32;

  if (tid < 32) { s_src[tid] = src[e0 + tid]; s_dst[tid] = dst[e0 + tid]; }

  // stage hH tile -> bf16 swizzled LDS. thread t: row=t>>3, 16B slot=t&7
  {
    int row = tid >> 3, slot = tid & 7;
    const float* p = &hH[(size_t)(e0 + row) * 64 + slot * 8];
    float4 a = *(const float4*)p;
    float4 b = *(const float4*)(p + 4);
    ushort u[8] = {f2bf(a.x), f2bf(a.y), f2bf(a.z), f2bf(a.w),
                   f2bf(b.x), f2bf(b.y), f2bf(b.z), f2bf(b.w)};
    *(uint4*)(hHb + row * 128 + ((slot * 16) ^ ((row & 7) << 4))) =
        *(const uint4*)u;
  }
  __syncthreads();  // s_src/s_dst + hHb visible

  // gather g = ni[src] + nj[dst] (bf16 in, f32 out), row-major swizzled
  {
    int m = tid & 31, cg0 = tid >> 5;
    const ushort* pi = ni_bf + (size_t)s_src[m] * 256;
    const ushort* pj = nj_bf + (size_t)s_dst[m] * 256;
    char* grow = gls + m * 1024;
    int swz = (m & 7) << 4;
#pragma unroll
    for (int i = 0; i < 4; ++i) {
      int c0 = (cg0 + i * 8) * 8;
      uint4 ui = *(const uint4*)(pi + c0);
      uint4 uj = *(const uint4*)(pj + c0);
      const ushort* si = (const ushort*)&ui;
      const ushort* sj = (const ushort*)&uj;
      float g[8];
#pragma unroll
      for (int j = 0; j < 8; ++j) g[j] = bf2f(si[j]) + bf2f(sj[j]);
      *(float4*)(grow + ((c0 * 4) ^ swz)) = make_float4(g[0], g[1], g[2], g[3]);
      *(float4*)(grow + (((c0 + 4) * 4) ^ swz)) =
          make_float4(g[4], g[5], g[6], g[7]);
    }
  }
  __syncthreads();

  const int w = tid >> 6, l = tid & 63;
  const int lr = l & 15, lk = l >> 4;
  const int swa = (lr & 7) << 4;

  // ---- GEMM1: f_pre[32][256] = hHb @ Wfij, wave slab cols [w*64, w*64+64)
  f32x4 acc[2][4];
#pragma unroll
  for (int mt = 0; mt < 2; ++mt)
#pragma unroll
    for (int nt = 0; nt < 4; ++nt) acc[mt][nt] = (f32x4){0.f, 0.f, 0.f, 0.f};

#pragma unroll
  for (int ks = 0; ks < 2; ++ks) {
    int ko = (ks * 32 + lk * 8) * 2;  // byte k-offset in a 128B row
    bf16x8 a0 = *(const bf16x8*)(hHb + lr * 128 + (ko ^ swa));
    bf16x8 a1 = *(const bf16x8*)(hHb + (16 + lr) * 128 + (ko ^ swa));
#pragma unroll
    for (int nt = 0; nt < 4; ++nt) {
      const ushort* bp =
          WfT + (size_t)(w * 64 + nt * 16 + lr) * 64 + ks * 32 + lk * 8;
      bf16x8 b = *(const bf16x8*)bp;
      acc[0][nt] = __builtin_amdgcn_mfma_f32_16x16x32_bf16(a0, b, acc[0][nt], 0, 0, 0);
      acc[1][nt] = __builtin_amdgcn_mfma_f32_16x16x32_bf16(a1, b, acc[1][nt], 0, 0, 0);
    }
  }

  // ---- + g, leaky, per-head attention logits (head == w)
  float av[4];
#pragma unroll
  for (int nt = 0; nt < 4; ++nt) av[nt] = attn[w * 64 + nt * 16 + lr];

#pragma unroll
  for (int mt = 0; mt < 2; ++mt) {
#pragma unroll
    for (int r = 0; r < 4; ++r) {
      int m = mt * 16 + lk * 4 + r;
      char* grow = gls + m * 1024;
      int swz = (m & 7) << 4;
      float p = 0.f;
#pragma unroll
      for (int nt = 0; nt < 4; ++nt) {
        int c = w * 64 + nt * 16 + lr;
        float gval = *(const float*)(grow + ((c * 4) ^ swz));
        float v = acc[mt][nt][r] + gval;
        v = (v >= 0.f) ? v : NEG_SLOPE * v;
        acc[mt][nt][r] = v;
        p += v * av[nt];
      }
      p += __shfl_xor(p, 1);
      p += __shfl_xor(p, 2);
      p += __shfl_xor(p, 4);
      p += __shfl_xor(p, 8);
      if (lr == 0) {
        e_ws[(size_t)(e0 + m) * 4 + w] = p;
        atomicMaxF32(&emax[(size_t)s_dst[m] * 4 + w], p);
      }
    }
  }
  __syncthreads();  // all g reads done; gls region reused for f_bf

  // ---- f -> bf16 LDS (A operand of GEMM2)
#pragma unroll
  for (int mt = 0; mt < 2; ++mt)
#pragma unroll
    for (int r = 0; r < 4; ++r) {
      int m = mt * 16 + lk * 4 + r;
      char* frow = gls + m * 512;
      int swz = (m & 7) << 4;
#pragma unroll
      for (int nt = 0; nt < 4; ++nt) {
        int c = w * 64 + nt * 16 + lr;
        *(ushort*)(frow + ((c * 2) ^ swz)) = f2bf(acc[mt][nt][r]);
      }
    }
  __syncthreads();

  // ---- GEMM2: out1[32][64] = f @ Wpe; wave w owns cols [w*16, w*16+16)
  f32x4 acc2[2];
  acc2[0] = (f32x4){0.f, 0.f, 0.f, 0.f};
  acc2[1] = (f32x4){0.f, 0.f, 0.f, 0.f};
  const ushort* bpW = WpeT + (size_t)(w * 16 + lr) * 256;
#pragma unroll
  for (int ks = 0; ks < 8; ++ks) {
    int ke = ks * 32 + lk * 8;
    bf16x8 b = *(const bf16x8*)(bpW + ke);
    bf16x8 a0 = *(const bf16x8*)(gls + lr * 512 + ((ke * 2) ^ swa));
    bf16x8 a1 = *(const bf16x8*)(gls + (16 + lr) * 512 + ((ke * 2) ^ swa));
    acc2[0] = __builtin_amdgcn_mfma_f32_16x16x32_bf16(a0, b, acc2[0], 0, 0, 0);
    acc2[1] = __builtin_amdgcn_mfma_f32_16x16x32_bf16(a1, b, acc2[1], 0, 0, 0);
  }

  // epilogue: + hH + bpe
  float bpv = bpe[w * 16 + lr];
#pragma unroll
  for (int mt = 0; mt < 2; ++mt)
#pragma unroll
    for (int r = 0; r < 4; ++r) {
      int m = mt * 16 + lk * 4 + r;
      size_t idx = (size_t)(e0 + m) * 64 + w * 16 + lr;
      out1[idx] = acc2[mt][r] + hH[idx] + bpv;
    }
}

// ---------------- K3a: a = exp(e - emax[dst]); asum += a ----------------
__global__ void k3a(const float* __restrict__ e_ws, const int* __restrict__ dst,
                    const float* __restrict__ emax, float* __restrict__ a_ws,
                    float* __restrict__ asum, int E4) {
  int gid = blockIdx.x * 256 + threadIdx.x;
  if (gid >= E4) return;
  int e = gid >> 2, h = gid & 3;
  int dn = dst[e];
  float av = expf(e_ws[gid] - emax[dn * 4 + h]);
  a_ws[gid] = av;
  atomicAdd(&asum[dn * 4 + h], av);
}

// ---------------- K3b: agg[dst] += sum_h (a/asum) * hq[src,h,:] ----------------
__global__ __launch_bounds__(256) void k3b(
    const float* __restrict__ a_ws, const float* __restrict__ asum,
    const int* __restrict__ src, const int* __restrict__ dst,
    const float* __restrict__ hq, float* __restrict__ agg, int E) {
  int e = blockIdx.x * 4 + (threadIdx.x >> 6);
  if (e >= E) return;
  int d = threadIdx.x & 63;
  int sn = src[e], dn = dst[e];
  float w0 = a_ws[e * 4 + 0] / asum[dn * 4 + 0];
  float w1 = a_ws[e * 4 + 1] / asum[dn * 4 + 1];
  float w2 = a_ws[e * 4 + 2] / asum[dn * 4 + 2];
  float w3 = a_ws[e * 4 + 3] / asum[dn * 4 + 3];
  const float* hqp = &hq[(size_t)sn * 256];
  float y = w0 * hqp[d] + w1 * hqp[64 + d] + w2 * hqp[128 + d] + w3 * hqp[192 + d];
  atomicAdd(&agg[(size_t)dn * 64 + d], y);
}

// ---------------- K4: out0 = hE + agg + bp_node ----------------
__global__ void k4(const float* __restrict__ hE, const float* __restrict__ agg,
                   const float* __restrict__ bpn, float* __restrict__ out0,
                   int ND) {
  int i = blockIdx.x * 256 + threadIdx.x;
  if (i < ND) out0[i] = hE[i] + agg[i] + bpn[i & 63];
}

extern "C" void kernel_launch(void* const* d_in, const int* in_sizes, int n_in,
                              void* d_out, int out_size, void* d_ws, size_t ws_size,
                              hipStream_t stream) {
  const float* h_E    = (const float*)d_in[0];
  const float* h_H    = (const float*)d_in[1];
  const int*   src    = (const int*)d_in[2];
  const int*   dst    = (const int*)d_in[3];
  const float* W_node = (const float*)d_in[4];
  const float* b_node = (const float*)d_in[5];
  const float* W_ni   = (const float*)d_in[6];
  const float* W_nj   = (const float*)d_in[7];
  const float* W_fij  = (const float*)d_in[8];
  const float* attn   = (const float*)d_in[9];
  const float* Wp_node= (const float*)d_in[10];
  const float* bp_node= (const float*)d_in[11];
  const float* Wp_edge= (const float*)d_in[12];
  const float* bp_edge= (const float*)d_in[13];

  const int n = in_sizes[0] / 64;   // 50000 nodes
  const int e = in_sizes[1] / 64;   // 800000 edges

  // workspace layout
  ushort* ws_ni  = (ushort*)d_ws;                     // n*256 bf16
  ushort* ws_nj  = ws_ni + (size_t)n * 256;           // n*256 bf16
  float*  ws_hq  = (float*)(ws_nj + (size_t)n * 256); // n*256 f32
  float*  ws_e   = ws_hq + (size_t)n * 256;           // e*4
  float*  ws_a   = ws_e + (size_t)e * 4;              // e*4
  float*  ws_emax= ws_a + (size_t)e * 4;              // n*4
  float*  ws_asum= ws_emax + (size_t)n * 4;           // n*4
  float*  ws_agg = ws_asum + (size_t)n * 4;           // n*64
  ushort* ws_WfT = (ushort*)(ws_agg + (size_t)n * 64);// 256*64 bf16
  ushort* ws_WpeT= ws_WfT + 16384;                    // 64*256 bf16

  float* out0 = (float*)d_out;               // (n,64)
  float* out1 = out0 + (size_t)n * 64;       // (e,64)

  {
    int total = n * 64;
    k_init<<<(total + 255) / 256, 256, 0, stream>>>(ws_emax, ws_asum, ws_agg, n);
  }
  k_prep<<<64, 256, 0, stream>>>(W_fij, Wp_edge, ws_WfT, ws_WpeT);
  {
    int blocks = (n + 31) / 32;
    k_node<<<blocks, 256, 0, stream>>>(h_E, W_ni, W_nj, W_node, b_node, Wp_node,
                                       ws_ni, ws_nj, ws_hq, n);
  }
  {
    int blocks = e / 32;  // E=800000 divisible by 32
    k_edge<<<blocks, 256, 0, stream>>>(h_H, src, dst, ws_WfT, attn, ws_WpeT,
                                       bp_edge, ws_ni, ws_nj, ws_e, ws_emax,
                                       out1);
  }
  {
    int total = e * 4;
    k3a<<<(total + 255) / 256, 256, 0, stream>>>(ws_e, dst, ws_emax, ws_a,
                                                 ws_asum, total);
  }
  {
    int blocks = (e + 3) / 4;
    k3b<<<blocks, 256, 0, stream>>>(ws_a, ws_asum, src, dst, ws_hq, ws_agg, e);
  }
  {
    int total = n * 64;
    k4<<<(total + 255) / 256, 256, 0, stream>>>(h_E, ws_agg, bp_node, out0,
                                                total);
  }
}